// Round 4
// baseline (31.496 us; speedup 1.0000x reference)
//
#include <hip/hip_runtime.h>

#define KC 256                  // codebook size
#define NROWS (8*64*64*64/4)    // 524288 rows of dim 4
#define RPT 4                   // rows per thread (512 blocks, 8 waves/CU)
#define TPB 256                 // threads per block
#define NG  (KC/4)              // 64 groups of 4 centers

// p = x.c_k - 0.5*||c_k||^2 ; argmax_k p  ==  argmin_k ||x - c_k||^2
__device__ __forceinline__ void score1(const float4 xv, const float4 c, const float mh,
                                       const int k, float& bestp, int& bestk) {
    float p = fmaf(xv.x, c.x, mh);
    p = fmaf(xv.y, c.y, p);
    p = fmaf(xv.z, c.z, p);
    p = fmaf(xv.w, c.w, p);
    if (p > bestp) { bestp = p; bestk = k; }   // strict '>': first index wins ties
}

__global__ __launch_bounds__(TPB) void vq_main(const float* __restrict__ x,
                                               const float* __restrict__ center,
                                               float* __restrict__ out) {
    __shared__ float4 sc[KC];     // codebook
    __shared__ float4 smh4[NG];   // -0.5*||c||^2, packed 4 per float4 (flat index == k)

    const int tid = threadIdx.x;
    {
        float4 c = reinterpret_cast<const float4*>(center)[tid];
        sc[tid] = c;
        float mh = -0.5f * (c.x * c.x + c.y * c.y + c.z * c.z + c.w * c.w);
        reinterpret_cast<float*>(smh4)[tid] = mh;   // float4[64] flat == float[256]
    }
    __syncthreads();

    const int base = blockIdx.x * (TPB * RPT) + tid;
    const float4* x4 = reinterpret_cast<const float4*>(x);

    float4 xv[RPT];
#pragma unroll
    for (int r = 0; r < RPT; ++r) xv[r] = x4[base + r * TPB];  // coalesced

    float bestp[RPT];
    int   bestk[RPT];
#pragma unroll
    for (int r = 0; r < RPT; ++r) { bestp[r] = -__builtin_inff(); bestk[r] = 0; }

    // 2-stage software pipeline over groups of 4 centers:
    // prefetch group g+1 (5 x ds_read_b128) while computing group g.
    float4 pc0 = sc[0], pc1 = sc[1], pc2 = sc[2], pc3 = sc[3];
    float4 pm  = smh4[0];

    for (int g = 0; g < NG; ++g) {
        const float4 c0 = pc0, c1 = pc1, c2 = pc2, c3 = pc3;
        const float4 m  = pm;
        if (g + 1 < NG) {
            const int b = 4 * (g + 1);
            pc0 = sc[b + 0]; pc1 = sc[b + 1]; pc2 = sc[b + 2]; pc3 = sc[b + 3];
            pm  = smh4[g + 1];
        }
        const int kb = 4 * g;
#pragma unroll
        for (int r = 0; r < RPT; ++r) {
            score1(xv[r], c0, m.x, kb + 0, bestp[r], bestk[r]);
            score1(xv[r], c1, m.y, kb + 1, bestp[r], bestk[r]);
            score1(xv[r], c2, m.z, kb + 2, bestp[r], bestk[r]);
            score1(xv[r], c3, m.w, kb + 3, bestp[r], bestk[r]);
        }
    }

#pragma unroll
    for (int r = 0; r < RPT; ++r) {
        reinterpret_cast<float4*>(out)[base + r * TPB] = sc[bestk[r]];  // LDS gather
    }
}

extern "C" void kernel_launch(void* const* d_in, const int* in_sizes, int n_in,
                              void* d_out, int out_size, void* d_ws, size_t ws_size,
                              hipStream_t stream) {
    const float* x      = (const float*)d_in[0];
    const float* center = (const float*)d_in[1];
    float* out = (float*)d_out;

    vq_main<<<NROWS / (TPB * RPT), TPB, 0, stream>>>(x, center, out);
}

// Round 7
// 28.833 us; speedup vs baseline: 1.0923x; 1.0923x over previous
//
#include <hip/hip_runtime.h>

#define KC 256                   // codebook size
#define NROWS (8*64*64*64/4)     // 524288 rows of dim 4
#define RPT 2                    // rows per thread
#define TPB 256                  // threads per block
#define NB (NROWS/(TPB*RPT))     // 1024 blocks -> 4 blocks/CU, 4 waves/SIMD
#define NG (KC/4)                // 64 chunks of 4 centers

// Per row: argmax_k (x.c_k - 0.5*||c_k||^2) == argmin_k ||x - c_k||^2.
// Codebook values arrive via the SCALAR path (uniform index -> s_load_dwordx16),
// so FMAs read them as SGPR operands: zero LDS broadcast cost for c.
// mh = -0.5*||c||^2 is computed once per block into LDS (can't reach SGPRs
// without a prep dispatch, which costs more in launch latency than it saves).
__global__ __launch_bounds__(TPB) void vq_main(const float* __restrict__ x,
                                               const float* __restrict__ center,
                                               float* __restrict__ out) {
    __shared__ float4 smh4[NG];    // -0.5*||c||^2, packed 4 per float4

    const int tid = threadIdx.x;
    {
        float4 c = reinterpret_cast<const float4*>(center)[tid];
        reinterpret_cast<float*>(smh4)[tid] =
            -0.5f * (c.x * c.x + c.y * c.y + c.z * c.z + c.w * c.w);
    }
    __syncthreads();

    const int base = blockIdx.x * (TPB * RPT) + tid;
    const float4* x4 = reinterpret_cast<const float4*>(x);
    const float4 xa = x4[base];
    const float4 xb = x4[base + TPB];

    float bpa = -__builtin_inff(), bpb = -__builtin_inff();
    int bka = 0, bkb = 0;

#pragma unroll 2
    for (int g = 0; g < NG; ++g) {
        // 16 consecutive floats of codebook, uniform address:
        // compiler merges to s_load_dwordx16 and inserts the lgkmcnt wait.
        float cv[16];
#pragma unroll
        for (int j = 0; j < 16; ++j) cv[j] = center[16 * g + j];

        const float4 m = smh4[g];          // uniform ds_read_b128 (broadcast)
        const float mj[4] = {m.x, m.y, m.z, m.w};

#pragma unroll
        for (int j = 0; j < 4; ++j) {
            const float cx = cv[4*j+0], cy = cv[4*j+1];
            const float cz = cv[4*j+2], cw = cv[4*j+3];
            const float mh = mj[j];
            const int k = 4 * g + j;
            // Same fma order + strict '>' as all previous passing rounds.
            float pa = fmaf(xa.x, cx, mh);
            pa = fmaf(xa.y, cy, pa);
            pa = fmaf(xa.z, cz, pa);
            pa = fmaf(xa.w, cw, pa);
            if (pa > bpa) { bpa = pa; bka = k; }
            float pb = fmaf(xb.x, cx, mh);
            pb = fmaf(xb.y, cy, pb);
            pb = fmaf(xb.z, cz, pb);
            pb = fmaf(xb.w, cw, pb);
            if (pb > bpb) { bpb = pb; bkb = k; }
        }
    }

    const float4* c4 = reinterpret_cast<const float4*>(center);  // 4KB, L1-resident
    reinterpret_cast<float4*>(out)[base]       = c4[bka];
    reinterpret_cast<float4*>(out)[base + TPB] = c4[bkb];
}

extern "C" void kernel_launch(void* const* d_in, const int* in_sizes, int n_in,
                              void* d_out, int out_size, void* d_ws, size_t ws_size,
                              hipStream_t stream) {
    const float* x      = (const float*)d_in[0];
    const float* center = (const float*)d_in[1];
    float* out = (float*)d_out;

    vq_main<<<NB, TPB, 0, stream>>>(x, center, out);
}